// Round 12
// baseline (12307.039 us; speedup 1.0000x reference)
//
#include <hip/hip_runtime.h>
#include <hip/hip_bf16.h>
#include <stdint.h>

#define HDIM 1024
#define TSEQ 4096
#define GATES3 3072   // 3*H
#define NTOT 6144     // 2*3*H

// d_ws layout: rz bf16 [0,32MB) | n32 f32 [32MB,64MB) | comm 32KB | xfin 8KB
#define COMM_OFF (64u * 1024 * 1024)
#define XFIN_OFF (COMM_OFF + 32768)

typedef __attribute__((ext_vector_type(8))) short short8;
typedef __attribute__((ext_vector_type(4))) float f32x4;
typedef __attribute__((ext_vector_type(4))) unsigned int ux4;
typedef unsigned long long u64;

__device__ __forceinline__ unsigned short f2bf(float f) {
    uint32_t u = __float_as_uint(f);
    uint32_t r = (u + 0x7FFFu + ((u >> 16) & 1u)) >> 16;
    return (unsigned short)r;
}
__device__ __forceinline__ float bf2f(unsigned short s) {
    return __uint_as_float(((uint32_t)s) << 16);
}

// agent-scope 16B poll load (r6-proven pairing with agent atomic publish)
__device__ __forceinline__ ux4 ld16_agent(const void* p) {
    ux4 r;
    asm volatile("global_load_dwordx4 %0, %1, off sc1\n\ts_waitcnt vmcnt(0)"
                 : "=v"(r) : "v"(p) : "memory");
    return r;
}
// system-scope fallback (r2/r5-proven)
__device__ __forceinline__ ux4 ld16_sys(const void* p) {
    ux4 r;
    asm volatile("global_load_dwordx4 %0, %1, off sc0 sc1\n\ts_waitcnt vmcnt(0)"
                 : "=v"(r) : "v"(p) : "memory");
    return r;
}

// ---------------------------------------------------------------------------
// init: invalidate all comm + xfin tags. Runs every call (graph-replay safe).
// ---------------------------------------------------------------------------
__global__ __launch_bounds__(256) void init_comm_kernel(uint8_t* __restrict__ wsb) {
    int i = blockIdx.x * 256 + threadIdx.x;   // grid 16x256 = 4096
    u64* comm = (u64*)(wsb + COMM_OFF);
    u64* xfin = (u64*)(wsb + XFIN_OFF);
    if (i < 4096) comm[i] = ~0ull;
    if (i < 1024) xfin[i] = ~0ull;
}

// ---------------------------------------------------------------------------
// x_proj GEMM (r3-proven, unchanged): emb[x] * w_ih^T + b_ih.
// r,z gates -> bf16 rz[T][4096]; n gate -> f32 n32[T][2048].
// ---------------------------------------------------------------------------
__global__ __launch_bounds__(256) void xproj_gemm_kernel(
    const int* __restrict__ x, const float* __restrict__ emb,
    const float* __restrict__ w_ih, const float* __restrict__ b_ih,
    unsigned short* __restrict__ rz, float* __restrict__ n32)
{
    __shared__ short As[128][32];
    __shared__ short Bs[128][32];

    const int tid = threadIdx.x;
    const int m0 = blockIdx.x * 128;
    const int n0 = blockIdx.y * 128;

    const int srow = tid >> 1;
    const int half = tid & 1;

    const int arow_g = x[m0 + srow];
    const float* aptr = emb + (size_t)arow_g * HDIM + half * 16;
    const float* bptr = w_ih + (size_t)(n0 + srow) * HDIM + half * 16;

    const int wid = tid >> 6;
    const int lane = tid & 63;
    const int wm = wid >> 1;
    const int wn = wid & 1;
    const int l15 = lane & 15;
    const int ksel = (lane >> 4) * 8;

    f32x4 acc[4][4];
    f32x4 zero4 = {0.f, 0.f, 0.f, 0.f};
#pragma unroll
    for (int mi = 0; mi < 4; mi++)
#pragma unroll
        for (int ni = 0; ni < 4; ni++) acc[mi][ni] = zero4;

    for (int k0 = 0; k0 < HDIM; k0 += 32) {
        float4 av[4], bv[4];
#pragma unroll
        for (int jj = 0; jj < 4; jj++) {
            av[jj] = *(const float4*)(aptr + k0 + jj * 4);
            bv[jj] = *(const float4*)(bptr + k0 + jj * 4);
        }
        if (k0) __syncthreads();
        short ta[16], tb[16];
#pragma unroll
        for (int jj = 0; jj < 4; jj++) {
            ta[jj*4+0] = f2bf(av[jj].x); ta[jj*4+1] = f2bf(av[jj].y);
            ta[jj*4+2] = f2bf(av[jj].z); ta[jj*4+3] = f2bf(av[jj].w);
            tb[jj*4+0] = f2bf(bv[jj].x); tb[jj*4+1] = f2bf(bv[jj].y);
            tb[jj*4+2] = f2bf(bv[jj].z); tb[jj*4+3] = f2bf(bv[jj].w);
        }
        *(short8*)&As[srow][half * 16]     = *(short8*)&ta[0];
        *(short8*)&As[srow][half * 16 + 8] = *(short8*)&ta[8];
        *(short8*)&Bs[srow][half * 16]     = *(short8*)&tb[0];
        *(short8*)&Bs[srow][half * 16 + 8] = *(short8*)&tb[8];
        __syncthreads();

        short8 af[4], bfr[4];
#pragma unroll
        for (int mi = 0; mi < 4; mi++)
            af[mi] = *(const short8*)&As[wm * 64 + mi * 16 + l15][ksel];
#pragma unroll
        for (int ni = 0; ni < 4; ni++)
            bfr[ni] = *(const short8*)&Bs[wn * 64 + ni * 16 + l15][ksel];
#pragma unroll
        for (int mi = 0; mi < 4; mi++)
#pragma unroll
            for (int ni = 0; ni < 4; ni++)
                acc[mi][ni] = __builtin_amdgcn_mfma_f32_16x16x32_bf16(
                    af[mi], bfr[ni], acc[mi][ni], 0, 0, 0);
    }

    const int r0 = m0 + wm * 64;
    const int c0 = n0 + wn * 64;
#pragma unroll
    for (int mi = 0; mi < 4; mi++) {
#pragma unroll
        for (int ni = 0; ni < 4; ni++) {
            int c = c0 + ni * 16 + l15;
            int dir = (c >= GATES3) ? 1 : 0;
            int g3 = c - dir * GATES3;
            int gate = g3 >> 10;
            int jj = g3 & 1023;
            float bias = b_ih[c];
#pragma unroll
            for (int v = 0; v < 4; v++) {
                int r = r0 + mi * 16 + (lane >> 4) * 4 + v;
                float val = acc[mi][ni][v] + bias;
                if (gate < 2)
                    rz[(size_t)r * 4096 + dir * 2048 + gate * 1024 + jj] = f2bf(val);
                else
                    n32[(size_t)r * 2048 + dir * 1024 + jj] = val;
            }
        }
    }
}

// ---------------------------------------------------------------------------
// Persistent recurrent kernel: 128 WGs x 512 threads (cooperative).
// dir = bid>>6, role = bid&63 owns j in [role*16, role*16+16).
// 32-lane group per output j; 32 h-cols per lane; 96 weight f32 in VGPRs.
// Comm: epoch-tagged 8B slots {tag32,val32}, parity ping-pong, agent scope
// (r6-proven protocol). NEW: x-gate loads software-pipelined one step ahead,
// issued AFTER the barrier so neither the poll's vmcnt(0) nor the barrier's
// pre-s_barrier drain ever waits on a young HBM load.
// ---------------------------------------------------------------------------
__global__ __launch_bounds__(512, 1) void rnn_kernel(
    const unsigned short* __restrict__ rz, const float* __restrict__ n32,
    const float* __restrict__ w_hh, const float* __restrict__ b_hh,
    uint8_t* __restrict__ wsb, float* __restrict__ out)
{
    // col c lives at LDS index (c>>5)*36 + (c&31): 16B-aligned chunks
    __shared__ float h_lds[2][1152];

    uint8_t* comm = wsb + COMM_OFF;
    u64* xfin = (u64*)(wsb + XFIN_OFF);

    const int tid = threadIdx.x;       // 0..511
    const int bid = blockIdx.x;
    const int dir = bid >> 6;
    const int role = bid & 63;
    const int g   = tid >> 5;          // 0..15
    const int sl  = tid & 31;          // lane in 32-lane group
    const int j   = role * 16 + g;

    // ---- persistent weights: rows {r,z,n} of w_hh[.,j,:], cols [sl*32,+32) ----
    f32x4 w0[8], w1[8], w2[8];
    {
        const float* Wd = w_hh + (size_t)dir * GATES3 * HDIM;
        const float* p0 = Wd + ((size_t)(0 * HDIM + j)) * HDIM + sl * 32;
        const float* p1 = Wd + ((size_t)(1 * HDIM + j)) * HDIM + sl * 32;
        const float* p2 = Wd + ((size_t)(2 * HDIM + j)) * HDIM + sl * 32;
#pragma unroll
        for (int c4 = 0; c4 < 8; c4++) {
            w0[c4] = *(const f32x4*)(p0 + c4 * 4);
            w1[c4] = *(const f32x4*)(p1 + c4 * 4);
            w2[c4] = *(const f32x4*)(p2 + c4 * 4);
        }
    }
    float bh0 = 0.f, bh1 = 0.f, bh2 = 0.f;
    if (sl == 0) {
        bh0 = b_hh[dir * GATES3 + j];
        bh1 = b_hh[dir * GATES3 + HDIM + j];
        bh2 = b_hh[dir * GATES3 + 2 * HDIM + j];
    }

    // comm addressing: slot(parity,dir,k) = comm + parity*16384 + dir*8192 + k*8
    uint8_t* commD = comm + dir * 8192;
    const uint8_t* poll0 = commD + (size_t)tid * 16;   // parity 0: slots 2tid,2tid+1
    const uint8_t* poll1 = poll0 + 16384;              // parity 1
    u64* slot0 = (u64*)(commD) + j;
    u64* slot1 = (u64*)(commD + 16384) + j;

    const int idx0 = (tid >> 4) * 36 + 2 * (tid & 15);  // LDS idx of col 2*tid
    const unsigned short* rzp = rz + dir * 2048 + j;
    const float* np = n32 + dir * 1024 + j;

    float last_h = 0.f;

    // ---- preload x-gates for t = 0 ----
    float xr = 0.f, xz = 0.f, xn = 0.f;
    if (sl == 0) {
        xr = bf2f(rzp[0]);
        xz = bf2f(rzp[1024]);
        xn = np[0];
    }
    rzp += 4096; np += 2048;

    for (int t = 0; t < TSEQ; t++) {
        const int buf = t & 1;

        // ---- stage h_{t-1}: poll own 2 slots with one 16B agent load ----
        if (t == 0) {
            h_lds[0][idx0]     = 0.f;
            h_lds[0][idx0 + 1] = 0.f;
        } else {
            const uint32_t want = (uint32_t)(t - 1);
            const uint8_t* src = ((t - 1) & 1) ? poll1 : poll0;
            ux4 v;
            int spins = 0;
            for (;;) {
                v = ld16_agent(src);
                if (v.x == want && v.z == want) break;
                if (++spins > (1 << 16)) {            // starvation insurance
                    v = ld16_sys(src);
                    if (v.x == want && v.z == want) break;
                    spins = (1 << 15);
                }
            }
            h_lds[buf][idx0]     = __uint_as_float(v.y);
            h_lds[buf][idx0 + 1] = __uint_as_float(v.w);
        }
        __syncthreads();   // only barrier per step (double-buffered LDS)

        // ---- prefetch x-gates for t+1 (AFTER the barrier: its pre-s_barrier
        // vmcnt(0) drain must not wait on these; they retire during
        // dot+reduce+finalize, long before the next poll's vmcnt(0)).
        // At t=TSEQ-1 this reads past rz/n32 into adjacent d_ws regions —
        // allocated memory, values unused.
        float nxr = 0.f, nxz = 0.f, nxn = 0.f;
        if (sl == 0) {
            nxr = bf2f(rzp[0]);
            nxz = bf2f(rzp[1024]);
            nxn = np[0];
        }
        rzp += 4096; np += 2048;

        // ---- dot: 3 gate rows x 32 cols ----
        f32x4 s0 = {0,0,0,0}, s1 = {0,0,0,0}, s2 = {0,0,0,0};
        const float* hb = &h_lds[buf][sl * 36];
#pragma unroll
        for (int c4 = 0; c4 < 8; c4++) {
            f32x4 hv = *(const f32x4*)(hb + c4 * 4);
            s0 += w0[c4] * hv;
            s1 += w1[c4] * hv;
            s2 += w2[c4] * hv;
        }
        float a0 = s0.x + s0.y + s0.z + s0.w;
        float a1 = s1.x + s1.y + s1.z + s1.w;
        float a2 = s2.x + s2.y + s2.z + s2.w;
#pragma unroll
        for (int m = 1; m < 32; m <<= 1) {
            a0 += __shfl_xor(a0, m, 32);
            a1 += __shfl_xor(a1, m, 32);
            a2 += __shfl_xor(a2, m, 32);
        }

        // ---- finalize + publish (hp = own last_h register, r9-proven) ----
        if (sl == 0) {
            float r  = 1.f / (1.f + __expf(-(xr + a0 + bh0)));
            float z  = 1.f / (1.f + __expf(-(xz + a1 + bh1)));
            float y  = xn + r * (a2 + bh2);
            float e2 = __expf(2.f * y);
            float n_ = 1.f - 2.f / (e2 + 1.f);      // tanh(y)
            float hnew = z * (last_h - n_) + n_;
            last_h = hnew;
            u64 pack = ((u64)__float_as_uint(hnew) << 32) | (uint32_t)t;
            __hip_atomic_store((t & 1) ? slot1 : slot0, pack,
                               __ATOMIC_RELAXED, __HIP_MEMORY_SCOPE_AGENT);
            // out row t directly from register (fire-and-forget, r9-proven)
            out[(size_t)t * 2048 + dir * 1024 + j] = hnew;
        }
        xr = nxr; xz = nxz; xn = nxn;
        // no trailing barrier (next step uses the other LDS buffer)
    }

    // hidden = h_last[0] + h_last[1]
    if (dir == 1 && sl == 0) {
        u64 pack = ((u64)__float_as_uint(last_h) << 32) | 0x0BADF00Du;
        __hip_atomic_store(&xfin[j], pack, __ATOMIC_RELAXED, __HIP_MEMORY_SCOPE_AGENT);
    }
    if (dir == 0 && sl == 0) {
        u64 v;
        do {
            v = __hip_atomic_load(&xfin[j], __ATOMIC_RELAXED, __HIP_MEMORY_SCOPE_AGENT);
        } while ((uint32_t)v != 0x0BADF00Du);
        out[(size_t)TSEQ * 2048 + j] = last_h + __uint_as_float((uint32_t)(v >> 32));
    }
}

// ---------------------------------------------------------------------------
extern "C" void kernel_launch(void* const* d_in, const int* in_sizes, int n_in,
                              void* d_out, int out_size, void* d_ws, size_t ws_size,
                              hipStream_t stream)
{
    const int*   x     = (const int*)d_in[0];
    const float* emb   = (const float*)d_in[1];
    const float* w_ih  = (const float*)d_in[2];
    const float* w_hh  = (const float*)d_in[3];
    const float* b_ih  = (const float*)d_in[4];
    const float* b_hh  = (const float*)d_in[5];
    float* out = (float*)d_out;

    unsigned short* rz  = (unsigned short*)d_ws;
    float* n32 = (float*)((char*)d_ws + (size_t)TSEQ * 4096 * 2);
    uint8_t* wsb = (uint8_t*)d_ws;

    init_comm_kernel<<<16, 256, 0, stream>>>(wsb);

    dim3 g(TSEQ / 128, NTOT / 128);
    xproj_gemm_kernel<<<g, 256, 0, stream>>>(x, emb, w_ih, b_ih, rz, n32);

    const unsigned short* a0 = rz;
    const float* a1 = n32;
    const float* a2 = w_hh;
    const float* a3 = b_hh;
    uint8_t* a4 = wsb;
    float* a5 = out;
    void* args[] = { (void*)&a0, (void*)&a1, (void*)&a2, (void*)&a3, (void*)&a4, (void*)&a5 };
    hipLaunchCooperativeKernel((void*)rnn_kernel, dim3(128), dim3(512), args, 0, stream);
}

// Round 13
// 7285.596 us; speedup vs baseline: 1.6892x; 1.6892x over previous
//
#include <hip/hip_runtime.h>
#include <hip/hip_bf16.h>
#include <stdint.h>

#define HDIM 1024
#define TSEQ 4096
#define GATES3 3072   // 3*H
#define NTOT 6144     // 2*3*H

// d_ws layout: rz bf16 [0,32MB) | n32 f32 [32MB,64MB) | comm 32KB | xfin 8KB
#define COMM_OFF (64u * 1024 * 1024)
#define XFIN_OFF (COMM_OFF + 32768)

typedef __attribute__((ext_vector_type(8))) short short8;
typedef __attribute__((ext_vector_type(4))) float f32x4;
typedef __attribute__((ext_vector_type(4))) unsigned int ux4;
typedef unsigned long long u64;

__device__ __forceinline__ unsigned short f2bf(float f) {
    uint32_t u = __float_as_uint(f);
    uint32_t r = (u + 0x7FFFu + ((u >> 16) & 1u)) >> 16;
    return (unsigned short)r;
}
__device__ __forceinline__ float bf2f(unsigned short s) {
    return __uint_as_float(((uint32_t)s) << 16);
}

// agent-scope 16B poll load (r6-proven pairing with agent-scope publish)
__device__ __forceinline__ ux4 ld16_agent(const void* p) {
    ux4 r;
    asm volatile("global_load_dwordx4 %0, %1, off sc1\n\ts_waitcnt vmcnt(0)"
                 : "=v"(r) : "v"(p) : "memory");
    return r;
}
// system-scope fallback (r2/r5-proven)
__device__ __forceinline__ ux4 ld16_sys(const void* p) {
    ux4 r;
    asm volatile("global_load_dwordx4 %0, %1, off sc0 sc1\n\ts_waitcnt vmcnt(0)"
                 : "=v"(r) : "v"(p) : "memory");
    return r;
}
// agent-scope 16B paired publish (one store covers both slots of a poll granule)
__device__ __forceinline__ void st16_agent(void* p, ux4 v) {
    asm volatile("global_store_dwordx4 %0, %1, off sc1" :: "v"(p), "v"(v) : "memory");
}

// ---------------------------------------------------------------------------
// init: invalidate all comm + xfin tags. Runs every call (graph-replay safe).
// ---------------------------------------------------------------------------
__global__ __launch_bounds__(256) void init_comm_kernel(uint8_t* __restrict__ wsb) {
    int i = blockIdx.x * 256 + threadIdx.x;   // grid 16x256 = 4096
    u64* comm = (u64*)(wsb + COMM_OFF);
    u64* xfin = (u64*)(wsb + XFIN_OFF);
    if (i < 4096) comm[i] = ~0ull;
    if (i < 1024) xfin[i] = ~0ull;
}

// ---------------------------------------------------------------------------
// x_proj GEMM (r3-proven, unchanged): emb[x] * w_ih^T + b_ih.
// r,z gates -> bf16 rz[T][4096]; n gate -> f32 n32[T][2048].
// ---------------------------------------------------------------------------
__global__ __launch_bounds__(256) void xproj_gemm_kernel(
    const int* __restrict__ x, const float* __restrict__ emb,
    const float* __restrict__ w_ih, const float* __restrict__ b_ih,
    unsigned short* __restrict__ rz, float* __restrict__ n32)
{
    __shared__ short As[128][32];
    __shared__ short Bs[128][32];

    const int tid = threadIdx.x;
    const int m0 = blockIdx.x * 128;
    const int n0 = blockIdx.y * 128;

    const int srow = tid >> 1;
    const int half = tid & 1;

    const int arow_g = x[m0 + srow];
    const float* aptr = emb + (size_t)arow_g * HDIM + half * 16;
    const float* bptr = w_ih + (size_t)(n0 + srow) * HDIM + half * 16;

    const int wid = tid >> 6;
    const int lane = tid & 63;
    const int wm = wid >> 1;
    const int wn = wid & 1;
    const int l15 = lane & 15;
    const int ksel = (lane >> 4) * 8;

    f32x4 acc[4][4];
    f32x4 zero4 = {0.f, 0.f, 0.f, 0.f};
#pragma unroll
    for (int mi = 0; mi < 4; mi++)
#pragma unroll
        for (int ni = 0; ni < 4; ni++) acc[mi][ni] = zero4;

    for (int k0 = 0; k0 < HDIM; k0 += 32) {
        float4 av[4], bv[4];
#pragma unroll
        for (int jj = 0; jj < 4; jj++) {
            av[jj] = *(const float4*)(aptr + k0 + jj * 4);
            bv[jj] = *(const float4*)(bptr + k0 + jj * 4);
        }
        if (k0) __syncthreads();
        short ta[16], tb[16];
#pragma unroll
        for (int jj = 0; jj < 4; jj++) {
            ta[jj*4+0] = f2bf(av[jj].x); ta[jj*4+1] = f2bf(av[jj].y);
            ta[jj*4+2] = f2bf(av[jj].z); ta[jj*4+3] = f2bf(av[jj].w);
            tb[jj*4+0] = f2bf(bv[jj].x); tb[jj*4+1] = f2bf(bv[jj].y);
            tb[jj*4+2] = f2bf(bv[jj].z); tb[jj*4+3] = f2bf(bv[jj].w);
        }
        *(short8*)&As[srow][half * 16]     = *(short8*)&ta[0];
        *(short8*)&As[srow][half * 16 + 8] = *(short8*)&ta[8];
        *(short8*)&Bs[srow][half * 16]     = *(short8*)&tb[0];
        *(short8*)&Bs[srow][half * 16 + 8] = *(short8*)&tb[8];
        __syncthreads();

        short8 af[4], bfr[4];
#pragma unroll
        for (int mi = 0; mi < 4; mi++)
            af[mi] = *(const short8*)&As[wm * 64 + mi * 16 + l15][ksel];
#pragma unroll
        for (int ni = 0; ni < 4; ni++)
            bfr[ni] = *(const short8*)&Bs[wn * 64 + ni * 16 + l15][ksel];
#pragma unroll
        for (int mi = 0; mi < 4; mi++)
#pragma unroll
            for (int ni = 0; ni < 4; ni++)
                acc[mi][ni] = __builtin_amdgcn_mfma_f32_16x16x32_bf16(
                    af[mi], bfr[ni], acc[mi][ni], 0, 0, 0);
    }

    const int r0 = m0 + wm * 64;
    const int c0 = n0 + wn * 64;
#pragma unroll
    for (int mi = 0; mi < 4; mi++) {
#pragma unroll
        for (int ni = 0; ni < 4; ni++) {
            int c = c0 + ni * 16 + l15;
            int dir = (c >= GATES3) ? 1 : 0;
            int g3 = c - dir * GATES3;
            int gate = g3 >> 10;
            int jj = g3 & 1023;
            float bias = b_ih[c];
#pragma unroll
            for (int v = 0; v < 4; v++) {
                int r = r0 + mi * 16 + (lane >> 4) * 4 + v;
                float val = acc[mi][ni][v] + bias;
                if (gate < 2)
                    rz[(size_t)r * 4096 + dir * 2048 + gate * 1024 + jj] = f2bf(val);
                else
                    n32[(size_t)r * 2048 + dir * 1024 + jj] = val;
            }
        }
    }
}

// ---------------------------------------------------------------------------
// Persistent recurrent kernel: 128 WGs x 512 threads (cooperative).
// EXACT r6 structure (7.07 ms proven) with two deltas:
//  (1) wave-paired publish: the 2 producers per wave exchange hnew via
//      __shfl_xor and lane 0 stores both slots as ONE 16B dwordx4 —
//      512 publish events/dir instead of 1024, consumer poll granule
//      filled atomically.
//  (2) hp = last_h register (drops an LDS read from finalize).
// ---------------------------------------------------------------------------
__global__ __launch_bounds__(512, 1) void rnn_kernel(
    const unsigned short* __restrict__ rz, const float* __restrict__ n32,
    const float* __restrict__ w_hh, const float* __restrict__ b_hh,
    uint8_t* __restrict__ wsb, float* __restrict__ out)
{
    // col c lives at LDS index (c>>5)*36 + (c&31): 16B-aligned chunks
    __shared__ float h_lds[2][1152];

    uint8_t* comm = wsb + COMM_OFF;
    u64* xfin = (u64*)(wsb + XFIN_OFF);

    const int tid = threadIdx.x;       // 0..511
    const int bid = blockIdx.x;
    const int dir = bid >> 6;
    const int role = bid & 63;
    const int g   = tid >> 5;          // 0..15
    const int sl  = tid & 31;          // lane in 32-lane group
    const int j   = role * 16 + g;

    // ---- persistent weights: rows {r,z,n} of w_hh[.,j,:], cols [sl*32,+32) ----
    f32x4 w0[8], w1[8], w2[8];
    {
        const float* Wd = w_hh + (size_t)dir * GATES3 * HDIM;
        const float* p0 = Wd + ((size_t)(0 * HDIM + j)) * HDIM + sl * 32;
        const float* p1 = Wd + ((size_t)(1 * HDIM + j)) * HDIM + sl * 32;
        const float* p2 = Wd + ((size_t)(2 * HDIM + j)) * HDIM + sl * 32;
#pragma unroll
        for (int c4 = 0; c4 < 8; c4++) {
            w0[c4] = *(const f32x4*)(p0 + c4 * 4);
            w1[c4] = *(const f32x4*)(p1 + c4 * 4);
            w2[c4] = *(const f32x4*)(p2 + c4 * 4);
        }
    }
    float bh0 = 0.f, bh1 = 0.f, bh2 = 0.f;
    if (sl == 0) {
        bh0 = b_hh[dir * GATES3 + j];
        bh1 = b_hh[dir * GATES3 + HDIM + j];
        bh2 = b_hh[dir * GATES3 + 2 * HDIM + j];
    }

    // comm addressing: slot(parity,dir,k) = comm + parity*16384 + dir*8192 + k*8
    uint8_t* commD = comm + dir * 8192;
    const uint8_t* poll0 = commD + (size_t)tid * 16;   // parity 0: slots 2tid,2tid+1
    const uint8_t* poll1 = poll0 + 16384;              // parity 1
    // paired publish base: wave w covers groups 2w,2w+1 -> slots j0=role*16+2w
    uint8_t* pairp = commD + (size_t)(role * 16 + 2 * (tid >> 6)) * 8;

    const int idx0 = (tid >> 4) * 36 + 2 * (tid & 15);  // LDS idx of col 2*tid
    const unsigned short* rzp = rz + dir * 2048 + j;
    const float* np = n32 + dir * 1024 + j;
    const int ocol = role * 16 + 2 * tid;               // tid<8: WG's out chunk
    const int oidx = (ocol >> 5) * 36 + (ocol & 31);

    float last_h = 0.f;

    for (int t = 0; t < TSEQ; t++) {
        const int buf = t & 1;

        // x-gates (issued BEFORE the poll: their drain overlaps the h-visibility
        // wait inside the first poll iteration — r6-proven placement, do not move)
        float xr = 0.f, xz = 0.f, xn = 0.f;
        if (sl == 0) {
            xr = bf2f(rzp[0]);
            xz = bf2f(rzp[1024]);
            xn = np[0];
        }
        rzp += 4096; np += 2048;

        // ---- stage h_{t-1}: poll own 2 slots with one 16B agent load ----
        if (t == 0) {
            h_lds[0][idx0]     = 0.f;
            h_lds[0][idx0 + 1] = 0.f;
        } else {
            const uint32_t want = (uint32_t)(t - 1);
            const uint8_t* src = ((t - 1) & 1) ? poll1 : poll0;
            ux4 v;
            int spins = 0;
            for (;;) {
                v = ld16_agent(src);
                if (v.x == want && v.z == want) break;
                if (++spins > (1 << 16)) {            // starvation insurance
                    v = ld16_sys(src);
                    if (v.x == want && v.z == want) break;
                    spins = (1 << 15);
                }
            }
            h_lds[buf][idx0]     = __uint_as_float(v.y);
            h_lds[buf][idx0 + 1] = __uint_as_float(v.w);
        }
        __syncthreads();   // only barrier per step (double-buffered LDS)

        // write output row t-1 (each WG writes its own 64B chunk)
        if (t > 0 && tid < 8) {
            float2 hv = *(float2*)&h_lds[buf][oidx];
            *(float2*)(out + (size_t)(t - 1) * 2048 + dir * 1024 + ocol) = hv;
        }

        // ---- dot: 3 gate rows x 32 cols ----
        f32x4 s0 = {0,0,0,0}, s1 = {0,0,0,0}, s2 = {0,0,0,0};
        const float* hb = &h_lds[buf][sl * 36];
#pragma unroll
        for (int c4 = 0; c4 < 8; c4++) {
            f32x4 hv = *(const f32x4*)(hb + c4 * 4);
            s0 += w0[c4] * hv;
            s1 += w1[c4] * hv;
            s2 += w2[c4] * hv;
        }
        float a0 = s0.x + s0.y + s0.z + s0.w;
        float a1 = s1.x + s1.y + s1.z + s1.w;
        float a2 = s2.x + s2.y + s2.z + s2.w;
#pragma unroll
        for (int m = 1; m < 32; m <<= 1) {
            a0 += __shfl_xor(a0, m, 32);
            a1 += __shfl_xor(a1, m, 32);
            a2 += __shfl_xor(a2, m, 32);
        }

        // ---- finalize (hp = own last_h register) ----
        float hnew = 0.f;
        if (sl == 0) {
            float r  = 1.f / (1.f + __expf(-(xr + a0 + bh0)));
            float z  = 1.f / (1.f + __expf(-(xz + a1 + bh1)));
            float y  = xn + r * (a2 + bh2);
            float e2 = __expf(2.f * y);
            float n_ = 1.f - 2.f / (e2 + 1.f);      // tanh(y)
            hnew = z * (last_h - n_) + n_;
            last_h = hnew;
        }
        // ---- wave-paired publish: lanes 0 and 32 exchange, lane 0 stores 16B ----
        float hpart = __shfl_xor(hnew, 32);          // width 64: lane l <-> l^32
        if ((tid & 63) == 0) {
            ux4 pk;
            pk.x = (uint32_t)t; pk.y = __float_as_uint(hnew);
            pk.z = (uint32_t)t; pk.w = __float_as_uint(hpart);
            st16_agent(pairp + ((t & 1) ? 16384 : 0), pk);
        }
        // no trailing barrier (next step uses the other LDS buffer)
    }

    // final output row from registers (no poll needed)
    if (sl == 0)
        out[(size_t)(TSEQ - 1) * 2048 + dir * 1024 + j] = last_h;

    // hidden = h_last[0] + h_last[1]
    if (dir == 1 && sl == 0) {
        u64 pack = ((u64)__float_as_uint(last_h) << 32) | 0x0BADF00Du;
        __hip_atomic_store(&xfin[j], pack, __ATOMIC_RELAXED, __HIP_MEMORY_SCOPE_AGENT);
    }
    if (dir == 0 && sl == 0) {
        u64 v;
        do {
            v = __hip_atomic_load(&xfin[j], __ATOMIC_RELAXED, __HIP_MEMORY_SCOPE_AGENT);
        } while ((uint32_t)v != 0x0BADF00Du);
        out[(size_t)TSEQ * 2048 + j] = last_h + __uint_as_float((uint32_t)(v >> 32));
    }
}

// ---------------------------------------------------------------------------
extern "C" void kernel_launch(void* const* d_in, const int* in_sizes, int n_in,
                              void* d_out, int out_size, void* d_ws, size_t ws_size,
                              hipStream_t stream)
{
    const int*   x     = (const int*)d_in[0];
    const float* emb   = (const float*)d_in[1];
    const float* w_ih  = (const float*)d_in[2];
    const float* w_hh  = (const float*)d_in[3];
    const float* b_ih  = (const float*)d_in[4];
    const float* b_hh  = (const float*)d_in[5];
    float* out = (float*)d_out;

    unsigned short* rz  = (unsigned short*)d_ws;
    float* n32 = (float*)((char*)d_ws + (size_t)TSEQ * 4096 * 2);
    uint8_t* wsb = (uint8_t*)d_ws;

    init_comm_kernel<<<16, 256, 0, stream>>>(wsb);

    dim3 g(TSEQ / 128, NTOT / 128);
    xproj_gemm_kernel<<<g, 256, 0, stream>>>(x, emb, w_ih, b_ih, rz, n32);

    const unsigned short* a0 = rz;
    const float* a1 = n32;
    const float* a2 = w_hh;
    const float* a3 = b_hh;
    uint8_t* a4 = wsb;
    float* a5 = out;
    void* args[] = { (void*)&a0, (void*)&a1, (void*)&a2, (void*)&a3, (void*)&a4, (void*)&a5 };
    hipLaunchCooperativeKernel((void*)rnn_kernel, dim3(128), dim3(512), args, 0, stream);
}